// Round 2
// baseline (1538.778 us; speedup 1.0000x reference)
//
#include <hip/hip_runtime.h>
#include <hip/hip_bf16.h>
#include <math.h>

// Problem constants (from reference)
#define B_SZ   128
#define HDIM   256
#define NG     1280     // 5*H
#define NNODES 1023
#define VOCAB  2048

typedef unsigned int  uint32;
typedef unsigned short ushort16;

__device__ __forceinline__ float sigm(float x) {
    return 1.0f / (1.0f + __expf(-x));
}
__device__ __forceinline__ float tanh_fast(float x) {
    // tanh(x) = 2*sigmoid(2x) - 1 ; saturates correctly for large |x|
    return 2.0f / (1.0f + __expf(-2.0f * x)) - 1.0f;
}
__device__ __forceinline__ float bf2f(unsigned short u) {
    return __uint_as_float(((uint32)u) << 16);
}
__device__ __forceinline__ unsigned short f2bf(float f) {
    uint32 x = __float_as_uint(f);
    uint32 r = (x + 0x7FFFu + ((x >> 16) & 1u)) >> 16;   // round-to-nearest-even
    return (unsigned short)r;
}

// ---------------------------------------------------------------------------
// EW = emb @ Wx + b  : (2048 x 1280) fp32, K=256.  64x64 tile, 256 thr, 4x4.
// ---------------------------------------------------------------------------
__global__ __launch_bounds__(256) void ew_kernel(
    const float* __restrict__ emb, const float* __restrict__ Wx,
    const float* __restrict__ bias, float* __restrict__ EW)
{
    __shared__ float As[16][76];   // A^T [k][row], pad 76 (16B-aligned rows)
    __shared__ float Bs[16][72];   // [k][col], pad 72

    const int tid = threadIdx.x;
    const int tx = tid & 15, ty = tid >> 4;
    const int rowBase = blockIdx.x * 64;
    const int colBase = blockIdx.y * 64;

    const int a_rr = tid >> 2, a_kq = tid & 3;
    const int b_kk = tid >> 4, b_c4 = tid & 15;

    float acc[4][4] = {};

    for (int kb = 0; kb < 256; kb += 16) {
        float4 av = *(const float4*)(emb + (size_t)(rowBase + a_rr) * 256 + kb + a_kq * 4);
        float4 bv = *(const float4*)(Wx + (size_t)(kb + b_kk) * NG + colBase + b_c4 * 4);
        __syncthreads();
        As[a_kq * 4 + 0][a_rr] = av.x;
        As[a_kq * 4 + 1][a_rr] = av.y;
        As[a_kq * 4 + 2][a_rr] = av.z;
        As[a_kq * 4 + 3][a_rr] = av.w;
        *(float4*)&Bs[b_kk][b_c4 * 4] = bv;
        __syncthreads();
        #pragma unroll
        for (int k = 0; k < 16; ++k) {
            float4 a = *(const float4*)&As[k][ty * 4];
            float4 b = *(const float4*)&Bs[k][tx * 4];
            acc[0][0] += a.x * b.x; acc[0][1] += a.x * b.y; acc[0][2] += a.x * b.z; acc[0][3] += a.x * b.w;
            acc[1][0] += a.y * b.x; acc[1][1] += a.y * b.y; acc[1][2] += a.y * b.z; acc[1][3] += a.y * b.w;
            acc[2][0] += a.z * b.x; acc[2][1] += a.z * b.y; acc[2][2] += a.z * b.z; acc[2][3] += a.z * b.w;
            acc[3][0] += a.w * b.x; acc[3][1] += a.w * b.y; acc[3][2] += a.w * b.z; acc[3][3] += a.w * b.w;
        }
    }

    #pragma unroll
    for (int u = 0; u < 4; ++u) {
        const int row = rowBase + ty * 4 + u;
        const int col = colBase + tx * 4;
        float4 bb = *(const float4*)(bias + col);
        float4 o;
        o.x = acc[u][0] + bb.x; o.y = acc[u][1] + bb.y;
        o.z = acc[u][2] + bb.z; o.w = acc[u][3] + bb.w;
        *(float4*)(EW + (size_t)row * NG + col) = o;
    }
}

// ---------------------------------------------------------------------------
// Leaf level (d=9): gates = EW[tok]; c = i*u; h = o*tanh(c).
// Writes bf16 h/c at LOCAL node index 0..511 into slot A.
// ---------------------------------------------------------------------------
__global__ __launch_bounds__(256) void leaf_kernel(
    const float* __restrict__ EW, const int* __restrict__ tokens,
    unsigned short* __restrict__ hdst, unsigned short* __restrict__ cdst)
{
    const int r = blockIdx.x;            // 0 .. B*512-1
    const int b = r >> 9, i = r & 511;
    const int node = 511 + i;            // global node id (for token lookup)
    const int tok = tokens[b * NNODES + node];
    const float* ew = EW + (size_t)tok * NG;
    const int j = threadIdx.x;

    const float gi = ew[j], go = ew[768 + j], gu = ew[1024 + j];
    const float ii = sigm(gi), oo = sigm(go), uu = tanh_fast(gu);
    const float c = ii * uu;
    const float h = oo * tanh_fast(c);
    const size_t oidx = ((size_t)i * B_SZ + b) * HDIM + j;   // LOCAL index
    hdst[oidx] = f2bf(h);
    cdst[oidx] = f2bf(c);
}

// ---------------------------------------------------------------------------
// Inner level d (8..0): fused GEMM ([hl|hr] @ [Ul;Ur], K=512, N=5*H) + gather
// of EW[tok] + LSTM cell + bf16 h/c write (local indices, ping-pong slots).
// Block tile: 64 rows x 32 cols(H) x 5 gates. 256 threads, 40 acc each.
// ---------------------------------------------------------------------------
__global__ __launch_bounds__(256) void level_kernel(
    const float* __restrict__ Ul, const float* __restrict__ Ur,
    const float* __restrict__ EW, const int* __restrict__ tokens,
    const unsigned short* __restrict__ hsrc, const unsigned short* __restrict__ csrc,
    unsigned short* __restrict__ hdst, unsigned short* __restrict__ cdst,
    float* __restrict__ out, const int d)
{
    const int n = 1 << d;
    const int start = n - 1;             // global node offset of this level

    __shared__ float As[16][76];          // A^T [k][row] fp32, pad 76
    __shared__ float Bs[16 * 160];        // [k][5*32] weight tile fp32

    const int tid = threadIdx.x;
    const int tx = tid & 15, ty = tid >> 4;
    const int rowBase = blockIdx.x * 64;
    const int colBase = blockIdx.y * 32;  // within H

    // ---- A loader setup: 64 rows x 16 k bf16 per step; 4 bf16/thread ----
    const int a_rr = tid >> 2, a_kq = tid & 3;
    const int a_r = rowBase + a_rr;
    const int a_b = a_r >> d, a_i = a_r & (n - 1);
    const unsigned short* hl_row = hsrc + ((size_t)(2 * a_i)     * B_SZ + a_b) * HDIM;
    const unsigned short* hr_row = hsrc + ((size_t)(2 * a_i + 1) * B_SZ + a_b) * HDIM;

    // ---- B loader setup: 640 float4 per K-step -> idx = tid, tid+256, tid+512 ----
    int bw_k[3], bw_off[3], bw_col[3];
    #pragma unroll
    for (int t = 0; t < 3; ++t) {
        const int idx = tid + t * 256;
        const int kk = idx / 40, q = idx % 40;
        const int g = q >> 3, jj = (q & 7) * 4;
        bw_k[t] = kk;
        bw_off[t] = kk * 160 + q * 4;
        bw_col[t] = g * 256 + colBase + jj;
    }
    const bool bw3 = (tid < 128);

    float acc[5][4][2] = {};

    for (int kb = 0; kb < 512; kb += 16) {
        const unsigned short* asrc = (kb < 256) ? (hl_row + kb) : (hr_row + (kb - 256));
        const ushort4 av = *(const ushort4*)(asrc + a_kq * 4);

        float4 bv0, bv1, bv2;
        {
            const int kg0 = kb + bw_k[0];
            bv0 = (kg0 < 256) ? *(const float4*)(Ul + (size_t)kg0 * NG + bw_col[0])
                              : *(const float4*)(Ur + (size_t)(kg0 - 256) * NG + bw_col[0]);
            const int kg1 = kb + bw_k[1];
            bv1 = (kg1 < 256) ? *(const float4*)(Ul + (size_t)kg1 * NG + bw_col[1])
                              : *(const float4*)(Ur + (size_t)(kg1 - 256) * NG + bw_col[1]);
            if (bw3) {
                const int kg2 = kb + bw_k[2];
                bv2 = (kg2 < 256) ? *(const float4*)(Ul + (size_t)kg2 * NG + bw_col[2])
                                  : *(const float4*)(Ur + (size_t)(kg2 - 256) * NG + bw_col[2]);
            }
        }

        __syncthreads();
        As[a_kq * 4 + 0][a_rr] = bf2f(av.x);
        As[a_kq * 4 + 1][a_rr] = bf2f(av.y);
        As[a_kq * 4 + 2][a_rr] = bf2f(av.z);
        As[a_kq * 4 + 3][a_rr] = bf2f(av.w);
        *(float4*)&Bs[bw_off[0]] = bv0;
        *(float4*)&Bs[bw_off[1]] = bv1;
        if (bw3) *(float4*)&Bs[bw_off[2]] = bv2;
        __syncthreads();

        #pragma unroll
        for (int k = 0; k < 16; ++k) {
            const float4 a = *(const float4*)&As[k][ty * 4];
            #pragma unroll
            for (int g = 0; g < 5; ++g) {
                const float2 b = *(const float2*)&Bs[k * 160 + g * 32 + tx * 2];
                acc[g][0][0] += a.x * b.x; acc[g][0][1] += a.x * b.y;
                acc[g][1][0] += a.y * b.x; acc[g][1][1] += a.y * b.y;
                acc[g][2][0] += a.z * b.x; acc[g][2][1] += a.z * b.y;
                acc[g][3][0] += a.w * b.x; acc[g][3][1] += a.w * b.y;
            }
        }
    }

    // ---- Epilogue: gather EW[tok], LSTM cell, write bf16 h/c (local idx) ----
    const int j = colBase + tx * 2;
    #pragma unroll
    for (int u = 0; u < 4; ++u) {
        const int r = rowBase + ty * 4 + u;
        const int b = r >> d, i = r & (n - 1);
        const int node = start + i;                       // global (tokens)
        const int tok = tokens[b * NNODES + node];
        const float* ew = EW + (size_t)tok * NG;
        const float2 e_i  = *(const float2*)(ew + j);
        const float2 e_fl = *(const float2*)(ew + 256 + j);
        const float2 e_fr = *(const float2*)(ew + 512 + j);
        const float2 e_o  = *(const float2*)(ew + 768 + j);
        const float2 e_u  = *(const float2*)(ew + 1024 + j);
        const ushort2 clu = *(const ushort2*)(csrc + ((size_t)(2 * i)     * B_SZ + b) * HDIM + j);
        const ushort2 cru = *(const ushort2*)(csrc + ((size_t)(2 * i + 1) * B_SZ + b) * HDIM + j);
        const float clx = bf2f(clu.x), cly = bf2f(clu.y);
        const float crx = bf2f(cru.x), cry = bf2f(cru.y);

        float hvx, hvy, cvx, cvy;
        {
            const float ii = sigm(e_i.x  + acc[0][u][0]);
            const float fl = sigm(e_fl.x + acc[1][u][0]);
            const float fr = sigm(e_fr.x + acc[2][u][0]);
            const float oo = sigm(e_o.x  + acc[3][u][0]);
            const float uu = tanh_fast(e_u.x + acc[4][u][0]);
            cvx = ii * uu + fl * clx + fr * crx;
            hvx = oo * tanh_fast(cvx);
        }
        {
            const float ii = sigm(e_i.y  + acc[0][u][1]);
            const float fl = sigm(e_fl.y + acc[1][u][1]);
            const float fr = sigm(e_fr.y + acc[2][u][1]);
            const float oo = sigm(e_o.y  + acc[3][u][1]);
            const float uu = tanh_fast(e_u.y + acc[4][u][1]);
            cvy = ii * uu + fl * cly + fr * cry;
            hvy = oo * tanh_fast(cvy);
        }
        const size_t oidx = ((size_t)i * B_SZ + b) * HDIM + j;    // LOCAL index
        ushort2 hu; hu.x = f2bf(hvx); hu.y = f2bf(hvy);
        ushort2 cu; cu.x = f2bf(cvx); cu.y = f2bf(cvy);
        *(ushort2*)(hdst + oidx) = hu;
        *(ushort2*)(cdst + oidx) = cu;
        if (d == 0) {
            float2 ov; ov.x = hvx; ov.y = hvy;
            *(float2*)(out + (size_t)b * HDIM + j) = ov;          // fp32 output
        }
    }
}

// ---------------------------------------------------------------------------
extern "C" void kernel_launch(void* const* d_in, const int* in_sizes, int n_in,
                              void* d_out, int out_size, void* d_ws, size_t ws_size,
                              hipStream_t stream)
{
    const int*   tokens = (const int*)d_in[0];
    const float* emb    = (const float*)d_in[1];
    const float* Wx     = (const float*)d_in[2];
    const float* Ul     = (const float*)d_in[3];
    const float* Ur     = (const float*)d_in[4];
    const float* bias   = (const float*)d_in[5];
    float* out = (float*)d_out;

    // Workspace layout (ping-pong bf16 h/c; only child+current levels live):
    //   EW fp32:            2048*1280*4 = 10.49 MB
    //   hA,cA (512 nodes):  2 * 512*128*256*2 = 67.11 MB
    //   hB,cB (256 nodes):  2 * 256*128*256*2 = 33.55 MB
    //   total = 111.15 MB
    const size_t EW_ELEMS = (size_t)VOCAB * NG;
    const size_t SLOT_A   = (size_t)512 * B_SZ * HDIM;   // elements (bf16)
    const size_t SLOT_B   = (size_t)256 * B_SZ * HDIM;
    const size_t REQUIRED = EW_ELEMS * 4 + (SLOT_A + SLOT_B) * 2 * 2;
    if (ws_size < REQUIRED || d_ws == nullptr) return;   // clean fail (absmax ~= max|ref|), not a core dump

    char* ws = (char*)d_ws;
    float* EW = (float*)ws;
    unsigned short* hA = (unsigned short*)(ws + EW_ELEMS * 4);
    unsigned short* cA = hA + SLOT_A;
    unsigned short* hB = cA + SLOT_A;
    unsigned short* cB = hB + SLOT_B;

    // EW = emb @ Wx + b  (x@Wx becomes a gather of EW[tok])
    ew_kernel<<<dim3(VOCAB / 64, NG / 64), 256, 0, stream>>>(emb, Wx, bias, EW);

    // Leaf level d=9 -> slot A
    leaf_kernel<<<dim3(B_SZ * 512), 256, 0, stream>>>(EW, tokens, hA, cA);

    // Levels d=8..0: even d reads A writes B, odd d reads B writes A
    for (int d = 8; d >= 0; --d) {
        const int M = B_SZ << d;
        const bool evenD = ((d & 1) == 0);
        const unsigned short* hs = evenD ? hA : hB;
        const unsigned short* cs = evenD ? cA : cB;
        unsigned short* hd = evenD ? hB : hA;
        unsigned short* cd = evenD ? cB : cA;
        level_kernel<<<dim3(M / 64, HDIM / 32), 256, 0, stream>>>(
            Ul, Ur, EW, tokens, hs, cs, hd, cd, out, d);
    }
}

// Round 3
// 447.192 us; speedup vs baseline: 3.4410x; 3.4410x over previous
//
#include <hip/hip_runtime.h>
#include <hip/hip_bf16.h>
#include <math.h>

// Problem constants (from reference)
#define B_SZ   128
#define HDIM   256
#define NG     1280     // 5*H
#define NNODES 1023
#define VOCAB  2048

typedef unsigned int uint32;
typedef short  short8v  __attribute__((ext_vector_type(8)));   // 8 x bf16 (4 VGPR)
typedef float  float4v  __attribute__((ext_vector_type(4)));   // MFMA C/D frag

__device__ __forceinline__ float sigm(float x) {
    return 1.0f / (1.0f + __expf(-x));
}
__device__ __forceinline__ float tanh_fast(float x) {
    return 2.0f / (1.0f + __expf(-2.0f * x)) - 1.0f;
}
__device__ __forceinline__ float bf2f(unsigned short u) {
    return __uint_as_float(((uint32)u) << 16);
}
__device__ __forceinline__ unsigned short f2bf(float f) {
    uint32 x = __float_as_uint(f);
    uint32 r = (x + 0x7FFFu + ((x >> 16) & 1u)) >> 16;   // RNE
    return (unsigned short)r;
}

// ---------------------------------------------------------------------------
// EWb = bf16(emb @ Wx + b) : (2048 x 1280), K=256. 64x64 tile fp32 compute.
// ---------------------------------------------------------------------------
__global__ __launch_bounds__(256) void ew_kernel(
    const float* __restrict__ emb, const float* __restrict__ Wx,
    const float* __restrict__ bias, unsigned short* __restrict__ EWb)
{
    __shared__ float As[16][76];
    __shared__ float Bs[16][72];

    const int tid = threadIdx.x;
    const int tx = tid & 15, ty = tid >> 4;
    const int rowBase = blockIdx.x * 64;
    const int colBase = blockIdx.y * 64;

    const int a_rr = tid >> 2, a_kq = tid & 3;
    const int b_kk = tid >> 4, b_c4 = tid & 15;

    float acc[4][4] = {};

    for (int kb = 0; kb < 256; kb += 16) {
        float4 av = *(const float4*)(emb + (size_t)(rowBase + a_rr) * 256 + kb + a_kq * 4);
        float4 bv = *(const float4*)(Wx + (size_t)(kb + b_kk) * NG + colBase + b_c4 * 4);
        __syncthreads();
        As[a_kq * 4 + 0][a_rr] = av.x;
        As[a_kq * 4 + 1][a_rr] = av.y;
        As[a_kq * 4 + 2][a_rr] = av.z;
        As[a_kq * 4 + 3][a_rr] = av.w;
        *(float4*)&Bs[b_kk][b_c4 * 4] = bv;
        __syncthreads();
        #pragma unroll
        for (int k = 0; k < 16; ++k) {
            float4 a = *(const float4*)&As[k][ty * 4];
            float4 b = *(const float4*)&Bs[k][tx * 4];
            acc[0][0] += a.x * b.x; acc[0][1] += a.x * b.y; acc[0][2] += a.x * b.z; acc[0][3] += a.x * b.w;
            acc[1][0] += a.y * b.x; acc[1][1] += a.y * b.y; acc[1][2] += a.y * b.z; acc[1][3] += a.y * b.w;
            acc[2][0] += a.z * b.x; acc[2][1] += a.z * b.y; acc[2][2] += a.z * b.z; acc[2][3] += a.z * b.w;
            acc[3][0] += a.w * b.x; acc[3][1] += a.w * b.y; acc[3][2] += a.w * b.z; acc[3][3] += a.w * b.w;
        }
    }

    #pragma unroll
    for (int u = 0; u < 4; ++u) {
        const int row = rowBase + ty * 4 + u;
        const int col = colBase + tx * 4;
        float4 bb = *(const float4*)(bias + col);
        ushort4 ov;
        ov.x = f2bf(acc[u][0] + bb.x);
        ov.y = f2bf(acc[u][1] + bb.y);
        ov.z = f2bf(acc[u][2] + bb.z);
        ov.w = f2bf(acc[u][3] + bb.w);
        *(ushort4*)(EWb + (size_t)row * NG + col) = ov;
    }
}

// ---------------------------------------------------------------------------
// WTf: fragment-ready bf16 repack of [Ul;Ur] (K=512, N=1280) for MFMA B.
// Layout: short8 index = (ng*16 + ks)*64 + lane ;  lane = q*16 + c
//   holds B[k = ks*32 + q*8 + j][col = ng*16 + c],  j = 0..7
// ---------------------------------------------------------------------------
__global__ __launch_bounds__(256) void prep_wtf(
    const float* __restrict__ Ul, const float* __restrict__ Ur,
    unsigned short* __restrict__ WTf)
{
    const int t = blockIdx.x * 256 + threadIdx.x;   // 0..81919
    const int l = t & 63;
    const int q = l >> 4, c = l & 15;
    const int ks = (t >> 6) & 15;
    const int ng = t >> 10;                          // 0..79
    const int col = ng * 16 + c;
    const int k = ks * 32 + q * 8;
    const float* src = (k < 256) ? (Ul + (size_t)k * NG + col)
                                 : (Ur + (size_t)(k - 256) * NG + col);
    short8v v;
    #pragma unroll
    for (int j = 0; j < 8; ++j) v[j] = (short)f2bf(src[(size_t)j * NG]);
    *(short8v*)(WTf + (size_t)t * 8) = v;
}

// ---------------------------------------------------------------------------
// Leaf level (d=9): gates = EWb[tok]; c = i*u; h = o*tanh(c).
// ---------------------------------------------------------------------------
__global__ __launch_bounds__(256) void leaf_kernel(
    const unsigned short* __restrict__ EWb, const int* __restrict__ tokens,
    unsigned short* __restrict__ hdst, unsigned short* __restrict__ cdst)
{
    const int r = blockIdx.x;            // 0 .. B*512-1
    const int b = r >> 9, i = r & 511;
    const int node = 511 + i;
    const int tok = tokens[b * NNODES + node];
    const unsigned short* ew = EWb + (size_t)tok * NG;
    const int j = threadIdx.x;

    const float gi = bf2f(ew[j]), go = bf2f(ew[768 + j]), gu = bf2f(ew[1024 + j]);
    const float ii = sigm(gi), oo = sigm(go), uu = tanh_fast(gu);
    const float c = ii * uu;
    const float h = oo * tanh_fast(c);
    const size_t oidx = ((size_t)i * B_SZ + b) * HDIM + j;
    hdst[oidx] = f2bf(h);
    cdst[oidx] = f2bf(c);
}

// ---------------------------------------------------------------------------
// Inner level d (8..0): MFMA bf16 GEMM [hl|hr](MxK=512) @ W(Kx1280) fused with
// EW gather + LSTM cell. Block: 256 thr (4 waves), tile 64 rows x 64 hcols x
// 5 gates. Wave w owns h-col tile w and ALL 5 gates (cell fuses in-register).
// A double-buffered in LDS (frag-ready order); B register-direct from WTf.
// ---------------------------------------------------------------------------
__global__ __launch_bounds__(256) void level_kernel(
    const unsigned short* __restrict__ WTf, const unsigned short* __restrict__ EWb,
    const int* __restrict__ tokens,
    const unsigned short* __restrict__ hsrc, const unsigned short* __restrict__ csrc,
    unsigned short* __restrict__ hdst, unsigned short* __restrict__ cdst,
    float* __restrict__ out, const int d)
{
    const int n = 1 << d;

    __shared__ __align__(16) short Abuf[2][2048];   // 2 x 4 KB, frag-ready order

    const int tid  = threadIdx.x;
    const int lane = tid & 63;
    const int w    = tid >> 6;
    const int quad = lane >> 4, col15 = lane & 15;
    const int rowBase = blockIdx.x * 64;

    // ---- A stage setup: thread tid <-> LDS slot tid ----
    // slot = rt*64 + q*16 + m : A[row=rowBase+rt*16+m][k = kb + q*8 + j]
    const int s_rt = tid >> 6, s_q = (tid >> 4) & 3, s_m = tid & 15;
    const int s_row = rowBase + s_rt * 16 + s_m;
    const int s_b = s_row >> d, s_i = s_row & (n - 1);
    const unsigned short* hlp = hsrc + ((size_t)(2 * s_i)     * B_SZ + s_b) * HDIM + s_q * 8;
    const unsigned short* hrp = hsrc + ((size_t)(2 * s_i + 1) * B_SZ + s_b) * HDIM + s_q * 8;

    // ---- B pointers: wave w -> h-col tile w; gate g -> ng = g*16 + y*4 + w ----
    const short8v* bp[5];
    #pragma unroll
    for (int g = 0; g < 5; ++g)
        bp[g] = (const short8v*)WTf + ((size_t)(g * 16 + blockIdx.y * 4 + w) * (16 * 64)) + lane;

    float4v acc[4][5];
    #pragma unroll
    for (int rt = 0; rt < 4; ++rt)
        #pragma unroll
        for (int g = 0; g < 5; ++g)
            #pragma unroll
            for (int e = 0; e < 4; ++e) acc[rt][g][e] = 0.0f;

    short8v a_next = *(const short8v*)hlp;          // ks = 0 (kb=0 < 256)
    int pb = 0;

    for (int ks = 0; ks < 16; ++ks) {
        *(short8v*)&Abuf[pb][tid * 8] = a_next;
        __syncthreads();

        if (ks < 15) {
            const int kb = (ks + 1) * 32;
            const unsigned short* s = (kb < 256) ? (hlp + kb) : (hrp + (kb - 256));
            a_next = *(const short8v*)s;
        }

        short8v bfrag[5];
        #pragma unroll
        for (int g = 0; g < 5; ++g) { bfrag[g] = *bp[g]; bp[g] += 64; }

        short8v afrag[4];
        #pragma unroll
        for (int rt = 0; rt < 4; ++rt)
            afrag[rt] = *(const short8v*)&Abuf[pb][(rt * 64 + lane) * 8];

        #pragma unroll
        for (int rt = 0; rt < 4; ++rt)
            #pragma unroll
            for (int g = 0; g < 5; ++g)
                acc[rt][g] = __builtin_amdgcn_mfma_f32_16x16x32_bf16(
                    afrag[rt], bfrag[g], acc[rt][g], 0, 0, 0);

        pb ^= 1;
    }

    // ---- Epilogue: C layout col=lane&15, row=quad*4+reg (verified m89) ----
    const int j = blockIdx.y * 64 + w * 16 + col15;
    #pragma unroll
    for (int rt = 0; rt < 4; ++rt) {
        #pragma unroll
        for (int reg = 0; reg < 4; ++reg) {
            const int row = rowBase + rt * 16 + quad * 4 + reg;
            const int b = row >> d, i = row & (n - 1);
            const int tok = tokens[b * NNODES + (n - 1) + i];
            const unsigned short* ew = EWb + (size_t)tok * NG;
            const float gi  = acc[rt][0][reg] + bf2f(ew[j]);
            const float gfl = acc[rt][1][reg] + bf2f(ew[256 + j]);
            const float gfr = acc[rt][2][reg] + bf2f(ew[512 + j]);
            const float go  = acc[rt][3][reg] + bf2f(ew[768 + j]);
            const float gu  = acc[rt][4][reg] + bf2f(ew[1024 + j]);
            const float cl = bf2f(csrc[((size_t)(2 * i)     * B_SZ + b) * HDIM + j]);
            const float cr = bf2f(csrc[((size_t)(2 * i + 1) * B_SZ + b) * HDIM + j]);
            const float ii = sigm(gi), fl = sigm(gfl), fr = sigm(gfr), oo = sigm(go);
            const float uu = tanh_fast(gu);
            const float c = ii * uu + fl * cl + fr * cr;
            const float h = oo * tanh_fast(c);
            const size_t oidx = ((size_t)i * B_SZ + b) * HDIM + j;
            hdst[oidx] = f2bf(h);
            cdst[oidx] = f2bf(c);
            if (d == 0) out[(size_t)b * HDIM + j] = h;
        }
    }
}

// ---------------------------------------------------------------------------
extern "C" void kernel_launch(void* const* d_in, const int* in_sizes, int n_in,
                              void* d_out, int out_size, void* d_ws, size_t ws_size,
                              hipStream_t stream)
{
    const int*   tokens = (const int*)d_in[0];
    const float* emb    = (const float*)d_in[1];
    const float* Wx     = (const float*)d_in[2];
    const float* Ul     = (const float*)d_in[3];
    const float* Ur     = (const float*)d_in[4];
    const float* bias   = (const float*)d_in[5];
    float* out = (float*)d_out;

    // Workspace: EWb bf16 5.24 MB | WTf bf16 1.31 MB | hA,cA 67.1 MB | hB,cB 33.6 MB
    // total 107.2 MB (< round-1's passing 111.2 MB footprint)
    const size_t EW_ELEMS  = (size_t)VOCAB * NG;          // bf16
    const size_t WTF_ELEMS = (size_t)80 * 16 * 64 * 8;    // bf16
    const size_t SLOT_A    = (size_t)512 * B_SZ * HDIM;   // bf16 elements
    const size_t SLOT_B    = (size_t)256 * B_SZ * HDIM;
    const size_t REQUIRED  = (EW_ELEMS + WTF_ELEMS + 2 * (SLOT_A + SLOT_B)) * 2;
    if (ws_size < REQUIRED || d_ws == nullptr) return;    // clean fail, not a fault

    char* ws = (char*)d_ws;
    unsigned short* EWb = (unsigned short*)ws;
    unsigned short* WTf = EWb + EW_ELEMS;
    unsigned short* hA  = WTf + WTF_ELEMS;
    unsigned short* cA  = hA + SLOT_A;
    unsigned short* hB  = cA + SLOT_A;
    unsigned short* cB  = hB + SLOT_B;

    ew_kernel<<<dim3(VOCAB / 64, NG / 64), 256, 0, stream>>>(emb, Wx, bias, EWb);
    prep_wtf<<<dim3(320), 256, 0, stream>>>(Ul, Ur, WTf);
    leaf_kernel<<<dim3(B_SZ * 512), 256, 0, stream>>>(EWb, tokens, hA, cA);

    for (int d = 8; d >= 0; --d) {
        const int M = B_SZ << d;
        const bool evenD = ((d & 1) == 0);
        const unsigned short* hs = evenD ? hA : hB;
        const unsigned short* cs = evenD ? cA : cB;
        unsigned short* hd = evenD ? hB : hA;
        unsigned short* cd = evenD ? cB : cA;
        level_kernel<<<dim3(M / 64, 4), 256, 0, stream>>>(
            WTf, EWb, tokens, hs, cs, hd, cd, out, d);
    }
}